// Round 1
// baseline (614.336 us; speedup 1.0000x reference)
//
#include <hip/hip_runtime.h>
#include <cstdint>
#include <cstddef>

#define M_TOT 8192
#define N_TOT 4096
#define K_TOT 4096
#define RANK  16

// ---- 256x256 8-phase GEMM geometry ----
#define BM 256
#define BN 256
#define BK 64
#define NT (K_TOT / BK)   // 64 K-tiles

typedef float f32x4 __attribute__((ext_vector_type(4)));
typedef __bf16 bf16x8 __attribute__((ext_vector_type(8)));
typedef unsigned short u16x8 __attribute__((ext_vector_type(8)));

__device__ __forceinline__ unsigned short f32_to_bf16(float f) {
    union { float f; uint32_t u; } v; v.f = f;
    uint32_t r = v.u + (0x7fffu + ((v.u >> 16) & 1u));
    return (unsigned short)(r >> 16);
}

// width-16 async global->LDS. dst is wave-uniform base; HW writes lane i at base + i*16B.
__device__ __forceinline__ void gload_lds16(const void* g, void* l) {
    __builtin_amdgcn_global_load_lds(
        (const __attribute__((address_space(1))) void*)g,
        (__attribute__((address_space(3))) void*)l,
        16, 0, 0);
}

// ---------------- x fp32 -> bf16, 8 elems/thread, 16B stores ----------------
__global__ __launch_bounds__(256) void convert_x_kernel(const float* __restrict__ x,
                                                        unsigned short* __restrict__ xb,
                                                        int n8) {
    int i = blockIdx.x * 256 + threadIdx.x;
    if (i >= n8) return;
    float4 a = ((const float4*)x)[2 * (size_t)i];
    float4 b = ((const float4*)x)[2 * (size_t)i + 1];
    u16x8 o;
    o[0] = f32_to_bf16(a.x); o[1] = f32_to_bf16(a.y);
    o[2] = f32_to_bf16(a.z); o[3] = f32_to_bf16(a.w);
    o[4] = f32_to_bf16(b.x); o[5] = f32_to_bf16(b.y);
    o[6] = f32_to_bf16(b.z); o[7] = f32_to_bf16(b.w);
    *(u16x8*)&xb[(size_t)i * 8] = o;
}

// ---- W = dequant(q,scales) + up@down, bf16 [OUT][IN]. 4 rows/block. ----
__global__ __launch_bounds__(256) void build_w_kernel(const int* __restrict__ q,
                                                      const float* __restrict__ scales,
                                                      const float* __restrict__ up,
                                                      const float* __restrict__ down,
                                                      unsigned short* __restrict__ W) {
    const int o0 = blockIdx.x * 4;
    const int t = threadIdx.x;
    __shared__ float u[4][RANK];
    if (t < 64) u[t >> 4][t & 15] = up[(o0 + (t >> 4)) * RANK + (t & 15)];
    __syncthreads();

#pragma unroll
    for (int cc = 0; cc < 2; cc++) {
        const int c = t + 256 * cc;        // 8-elem chunk index, 0..511
        const int k0 = c * 8;
        float acc[4][8];
#pragma unroll
        for (int row = 0; row < 4; row++) {
            const int o = o0 + row;
            int4 qa = *(const int4*)&q[(size_t)o * K_TOT + k0];
            int4 qb = *(const int4*)&q[(size_t)o * K_TOT + k0 + 4];
            const float s = scales[o * (K_TOT / 32) + (k0 >> 5)];
            acc[row][0] = (float)(qa.x - 128) * s;
            acc[row][1] = (float)(qa.y - 128) * s;
            acc[row][2] = (float)(qa.z - 128) * s;
            acc[row][3] = (float)(qa.w - 128) * s;
            acc[row][4] = (float)(qb.x - 128) * s;
            acc[row][5] = (float)(qb.y - 128) * s;
            acc[row][6] = (float)(qb.z - 128) * s;
            acc[row][7] = (float)(qb.w - 128) * s;
        }
#pragma unroll
        for (int r = 0; r < RANK; r++) {
            float4 da = *(const float4*)&down[r * K_TOT + k0];
            float4 db = *(const float4*)&down[r * K_TOT + k0 + 4];
#pragma unroll
            for (int row = 0; row < 4; row++) {
                const float ur = u[row][r];
                acc[row][0] += ur * da.x; acc[row][1] += ur * da.y;
                acc[row][2] += ur * da.z; acc[row][3] += ur * da.w;
                acc[row][4] += ur * db.x; acc[row][5] += ur * db.y;
                acc[row][6] += ur * db.z; acc[row][7] += ur * db.w;
            }
        }
#pragma unroll
        for (int row = 0; row < 4; row++) {
            u16x8 o8;
#pragma unroll
            for (int j = 0; j < 8; j++) o8[j] = f32_to_bf16(acc[row][j]);
            *(u16x8*)&W[(size_t)(o0 + row) * K_TOT + k0] = o8;
        }
    }
}

// raw barrier (NO vmcnt drain — that drain is the m97 ceiling). Compiler memory
// fences pin load/store issue order around it.
#define BARRIER() do { asm volatile("" ::: "memory"); \
                       __builtin_amdgcn_s_barrier(); \
                       asm volatile("" ::: "memory"); } while (0)

// ---------------- C[m][n] = sum_k A[m][k]*B[n][k] + bias[n]  (bf16 K-major) ----------------
// 256x256 tile, BK=64, 8 waves (2Mx4N), 4 phases/K-tile, counted vmcnt(4) at tile end.
// LDS: 2 buf x {A,B} x 2 halves x [128 rows][64 cols] bf16 = 128 KB.
// Swizzle: row stride is 128 B (full bank wrap) -> store k-slot s of row r at slot s^(r&7).
// Staging pre-swizzles the GLOBAL source; LDS dst stays linear (global_load_lds constraint).
__global__ __launch_bounds__(512, 2) void gemm_bt_kernel(const unsigned short* __restrict__ A,
                                                         const unsigned short* __restrict__ B,
                                                         const float* __restrict__ bias,
                                                         float* __restrict__ C) {
    __shared__ unsigned short As[2][2][128 * BK];   // [buf][half][row*64+col] 64 KB
    __shared__ unsigned short Bs[2][2][128 * BK];   // 64 KB

    const int tid  = (int)threadIdx.x;
    const int wave = tid >> 6;        // 0..7
    const int lane = tid & 63;
    const int wm   = wave >> 2;       // 0..1 : A half / 128-row strip
    const int wn   = wave & 3;        // 0..3 : 64-col strip
    const int wbh  = wn >> 1;         // B half
    const int wbr  = (wn & 1) * 64;   // row base within B half

    // XCD-bijective swizzle: nwg=512, 8 XCDs, 64 contiguous tiles per XCD
    int lin = (int)(blockIdx.y * gridDim.x + blockIdx.x);
    lin = (lin & 7) * 64 + (lin >> 3);
    const int tile_n = (lin & 15) * BN;   // 16 N-tiles
    const int tile_m = (lin >> 4) * BM;   // 32 M-tiles

    // staging constants: instr i covers rows i*64 + tid/8 of a half; lane's 16B chunk
    // fetches global k-group (tid&7) ^ (row&7)  (inverse swizzle at the source)
    const int srow  = tid >> 3;                         // 0..63
    const int sk    = ((tid & 7) ^ (srow & 7)) * 8;     // elem offset in 64-col group
    const int wbase = wave * 512;                       // wave-uniform LDS elem base

    // fragment-read constants (mfma_16x16x32: lane = quad*16+l16, A row=l16, k=quad*8)
    const int l16  = lane & 15;
    const int quad = lane >> 4;
    const int sw   = l16 & 7;
    const int slot0 = ((quad ^ sw) * 8);          // physical slot for k-slot quad   (kk=0)
    const int slot1 = (((4 + quad) ^ sw) * 8);    // physical slot for k-slot 4+quad (kk=1)

    const unsigned short* aBase = A + (size_t)(tile_m + srow) * K_TOT + sk;
    const unsigned short* bBase = B + (size_t)(tile_n + srow) * K_TOT + sk;

#define STAGE_A(d, h, t) do { \
    gload_lds16(aBase + (size_t)((h) * 128) * K_TOT + (size_t)(t) * BK, &As[d][h][wbase]); \
    gload_lds16(aBase + (size_t)((h) * 128 + 64) * K_TOT + (size_t)(t) * BK, &As[d][h][4096 + wbase]); \
  } while (0)
#define STAGE_B(d, h, t) do { \
    gload_lds16(bBase + (size_t)((h) * 128) * K_TOT + (size_t)(t) * BK, &Bs[d][h][wbase]); \
    gload_lds16(bBase + (size_t)((h) * 128 + 64) * K_TOT + (size_t)(t) * BK, &Bs[d][h][4096 + wbase]); \
  } while (0)

    f32x4 acc[8][4];
#pragma unroll
    for (int i = 0; i < 8; i++)
#pragma unroll
        for (int j = 0; j < 4; j++) { f32x4 z = {0.f, 0.f, 0.f, 0.f}; acc[i][j] = z; }

    // prologue: tile0 fully + A(1); wait leaves A(1)'s 4 loads in flight
    STAGE_A(0, 0, 0); STAGE_A(0, 1, 0);
    STAGE_B(0, 0, 0); STAGE_B(0, 1, 0);
    STAGE_A(1, 0, 1); STAGE_A(1, 1, 1);
    asm volatile("s_waitcnt vmcnt(4)" ::: "memory");
    BARRIER();

    for (int t = 0; t < NT; ++t) {
        const int cur = t & 1, nxt = cur ^ 1;
        const unsigned short* Ah = &As[cur][wm][l16 * BK];
        const unsigned short* Bh = &Bs[cur][wbh][(wbr + l16) * BK];

        bf16x8 af[4][2], bfA[2][2], bfB[2][2];

        // ---------------- P1: stage B0(t+1); read af[0-3], bfA; MFMA Q0 ----------------
        if (t + 1 < NT) STAGE_B(nxt, 0, t + 1);
#pragma unroll
        for (int mi = 0; mi < 4; mi++) {
            af[mi][0] = *(const bf16x8*)&Ah[(mi * 16) * BK + slot0];
            af[mi][1] = *(const bf16x8*)&Ah[(mi * 16) * BK + slot1];
        }
#pragma unroll
        for (int ni = 0; ni < 2; ni++) {
            bfA[ni][0] = *(const bf16x8*)&Bh[(ni * 16) * BK + slot0];
            bfA[ni][1] = *(const bf16x8*)&Bh[(ni * 16) * BK + slot1];
        }
        BARRIER();
        __builtin_amdgcn_s_setprio(1);
#pragma unroll
        for (int mi = 0; mi < 4; mi++)
#pragma unroll
            for (int ni = 0; ni < 2; ni++) {
                acc[mi][ni] = __builtin_amdgcn_mfma_f32_16x16x32_bf16(af[mi][0], bfA[ni][0], acc[mi][ni], 0, 0, 0);
                acc[mi][ni] = __builtin_amdgcn_mfma_f32_16x16x32_bf16(af[mi][1], bfA[ni][1], acc[mi][ni], 0, 0, 0);
            }
        __builtin_amdgcn_s_setprio(0);
        BARRIER();

        // ---------------- P2: stage B1(t+1); read bfB; MFMA Q1 (mi0-3 x ni2-3) ----------------
        if (t + 1 < NT) STAGE_B(nxt, 1, t + 1);
#pragma unroll
        for (int ni = 0; ni < 2; ni++) {
            bfB[ni][0] = *(const bf16x8*)&Bh[((ni + 2) * 16) * BK + slot0];
            bfB[ni][1] = *(const bf16x8*)&Bh[((ni + 2) * 16) * BK + slot1];
        }
        BARRIER();
        __builtin_amdgcn_s_setprio(1);
#pragma unroll
        for (int mi = 0; mi < 4; mi++)
#pragma unroll
            for (int ni = 0; ni < 2; ni++) {
                acc[mi][ni + 2] = __builtin_amdgcn_mfma_f32_16x16x32_bf16(af[mi][0], bfB[ni][0], acc[mi][ni + 2], 0, 0, 0);
                acc[mi][ni + 2] = __builtin_amdgcn_mfma_f32_16x16x32_bf16(af[mi][1], bfB[ni][1], acc[mi][ni + 2], 0, 0, 0);
            }
        __builtin_amdgcn_s_setprio(0);
        BARRIER();

        // ---------------- P3: read af[4-7] (reuse regs); MFMA Q2 (mi4-7 x ni2-3) ----------------
#pragma unroll
        for (int mi = 0; mi < 4; mi++) {
            af[mi][0] = *(const bf16x8*)&Ah[((mi + 4) * 16) * BK + slot0];
            af[mi][1] = *(const bf16x8*)&Ah[((mi + 4) * 16) * BK + slot1];
        }
        BARRIER();
        __builtin_amdgcn_s_setprio(1);
#pragma unroll
        for (int mi = 0; mi < 4; mi++)
#pragma unroll
            for (int ni = 0; ni < 2; ni++) {
                acc[mi + 4][ni + 2] = __builtin_amdgcn_mfma_f32_16x16x32_bf16(af[mi][0], bfB[ni][0], acc[mi + 4][ni + 2], 0, 0, 0);
                acc[mi + 4][ni + 2] = __builtin_amdgcn_mfma_f32_16x16x32_bf16(af[mi][1], bfB[ni][1], acc[mi + 4][ni + 2], 0, 0, 0);
            }
        __builtin_amdgcn_s_setprio(0);
        BARRIER();

        // -------- P4: stage A(t+2) into buf[cur] (A-reads done at P3); MFMA Q3; counted wait --------
        if (t + 2 < NT) { STAGE_A(cur, 0, t + 2); STAGE_A(cur, 1, t + 2); }
        __builtin_amdgcn_s_setprio(1);
#pragma unroll
        for (int mi = 0; mi < 4; mi++)
#pragma unroll
            for (int ni = 0; ni < 2; ni++) {
                acc[mi + 4][ni] = __builtin_amdgcn_mfma_f32_16x16x32_bf16(af[mi][0], bfA[ni][0], acc[mi + 4][ni], 0, 0, 0);
                acc[mi + 4][ni] = __builtin_amdgcn_mfma_f32_16x16x32_bf16(af[mi][1], bfA[ni][1], acc[mi + 4][ni], 0, 0, 0);
            }
        __builtin_amdgcn_s_setprio(0);
        if (t + 1 < NT) {
            if (t + 2 < NT) asm volatile("s_waitcnt vmcnt(4)" ::: "memory");  // A(t+1),B(t+1) landed; A(t+2) stays in flight
            else            asm volatile("s_waitcnt vmcnt(0)" ::: "memory");  // last-but-one tile: drain
        }
        BARRIER();
    }

    // epilogue: D row=(quad*4+r), col=l16 within each 16x16 tile
#pragma unroll
    for (int ni = 0; ni < 4; ni++) {
        const int col = tile_n + wn * 64 + ni * 16 + l16;
        const float bv = bias[col];
#pragma unroll
        for (int mi = 0; mi < 8; mi++) {
#pragma unroll
            for (int r = 0; r < 4; r++) {
                const int row = tile_m + wm * 128 + mi * 16 + quad * 4 + r;
                C[(size_t)row * N_TOT + col] = acc[mi][ni][r] + bv;
            }
        }
    }
#undef STAGE_A
#undef STAGE_B
}

extern "C" void kernel_launch(void* const* d_in, const int* in_sizes, int n_in,
                              void* d_out, int out_size, void* d_ws, size_t ws_size,
                              hipStream_t stream) {
    const float* x      = (const float*)d_in[0];
    const int*   q      = (const int*)d_in[1];
    const float* scales = (const float*)d_in[2];
    const float* up     = (const float*)d_in[3];
    const float* down   = (const float*)d_in[4];
    const float* bias   = (const float*)d_in[5];
    float* out = (float*)d_out;

    unsigned short* xb = (unsigned short*)d_ws;                 // 8192*4096 bf16 = 64 MB
    unsigned short* wb = xb + (size_t)M_TOT * K_TOT;            // 4096*4096 bf16 = 32 MB

    const int n8 = M_TOT * K_TOT / 8;
    convert_x_kernel<<<n8 / 256, 256, 0, stream>>>(x, xb, n8);
    build_w_kernel<<<N_TOT / 4, 256, 0, stream>>>(q, scales, up, down, wb);
    gemm_bt_kernel<<<dim3(N_TOT / BN, M_TOT / BM), 512, 0, stream>>>(xb, wb, bias, out);
}

// Round 3
// 597.996 us; speedup vs baseline: 1.0273x; 1.0273x over previous
//
#include <hip/hip_runtime.h>
#include <cstdint>
#include <cstddef>

#define M_TOT 8192
#define N_TOT 4096
#define K_TOT 4096
#define RANK  16

// ---- 256x256 8-phase GEMM geometry ----
#define BM 256
#define BN 256
#define BK 64
#define NT (K_TOT / BK)   // 64 K-tiles

typedef float f32x4 __attribute__((ext_vector_type(4)));
typedef __bf16 bf16x8 __attribute__((ext_vector_type(8)));
typedef unsigned short u16x8 __attribute__((ext_vector_type(8)));

__device__ __forceinline__ unsigned short f32_to_bf16(float f) {
    union { float f; uint32_t u; } v; v.f = f;
    uint32_t r = v.u + (0x7fffu + ((v.u >> 16) & 1u));
    return (unsigned short)(r >> 16);
}

// width-16 async global->LDS. dst is wave-uniform base; HW writes lane i at base + i*16B.
__device__ __forceinline__ void gload_lds16(const void* g, void* l) {
    __builtin_amdgcn_global_load_lds(
        (const __attribute__((address_space(1))) void*)g,
        (__attribute__((address_space(3))) void*)l,
        16, 0, 0);
}

// ---------------- x fp32 -> bf16, 8 elems/thread, 16B stores ----------------
__global__ __launch_bounds__(256) void convert_x_kernel(const float* __restrict__ x,
                                                        unsigned short* __restrict__ xb,
                                                        int n8) {
    int i = blockIdx.x * 256 + threadIdx.x;
    if (i >= n8) return;
    float4 a = ((const float4*)x)[2 * (size_t)i];
    float4 b = ((const float4*)x)[2 * (size_t)i + 1];
    u16x8 o;
    o[0] = f32_to_bf16(a.x); o[1] = f32_to_bf16(a.y);
    o[2] = f32_to_bf16(a.z); o[3] = f32_to_bf16(a.w);
    o[4] = f32_to_bf16(b.x); o[5] = f32_to_bf16(b.y);
    o[6] = f32_to_bf16(b.z); o[7] = f32_to_bf16(b.w);
    *(u16x8*)&xb[(size_t)i * 8] = o;
}

// ---- W = dequant(q,scales) + up@down, bf16 [OUT][IN]. 4 rows/block. ----
__global__ __launch_bounds__(256) void build_w_kernel(const int* __restrict__ q,
                                                      const float* __restrict__ scales,
                                                      const float* __restrict__ up,
                                                      const float* __restrict__ down,
                                                      unsigned short* __restrict__ W) {
    const int o0 = blockIdx.x * 4;
    const int t = threadIdx.x;
    __shared__ float u[4][RANK];
    if (t < 64) u[t >> 4][t & 15] = up[(o0 + (t >> 4)) * RANK + (t & 15)];
    __syncthreads();

#pragma unroll
    for (int cc = 0; cc < 2; cc++) {
        const int c = t + 256 * cc;        // 8-elem chunk index, 0..511
        const int k0 = c * 8;
        float acc[4][8];
#pragma unroll
        for (int row = 0; row < 4; row++) {
            const int o = o0 + row;
            int4 qa = *(const int4*)&q[(size_t)o * K_TOT + k0];
            int4 qb = *(const int4*)&q[(size_t)o * K_TOT + k0 + 4];
            const float s = scales[o * (K_TOT / 32) + (k0 >> 5)];
            acc[row][0] = (float)(qa.x - 128) * s;
            acc[row][1] = (float)(qa.y - 128) * s;
            acc[row][2] = (float)(qa.z - 128) * s;
            acc[row][3] = (float)(qa.w - 128) * s;
            acc[row][4] = (float)(qb.x - 128) * s;
            acc[row][5] = (float)(qb.y - 128) * s;
            acc[row][6] = (float)(qb.z - 128) * s;
            acc[row][7] = (float)(qb.w - 128) * s;
        }
#pragma unroll
        for (int r = 0; r < RANK; r++) {
            float4 da = *(const float4*)&down[r * K_TOT + k0];
            float4 db = *(const float4*)&down[r * K_TOT + k0 + 4];
#pragma unroll
            for (int row = 0; row < 4; row++) {
                const float ur = u[row][r];
                acc[row][0] += ur * da.x; acc[row][1] += ur * da.y;
                acc[row][2] += ur * da.z; acc[row][3] += ur * da.w;
                acc[row][4] += ur * db.x; acc[row][5] += ur * db.y;
                acc[row][6] += ur * db.z; acc[row][7] += ur * db.w;
            }
        }
#pragma unroll
        for (int row = 0; row < 4; row++) {
            u16x8 o8;
#pragma unroll
            for (int j = 0; j < 8; j++) o8[j] = f32_to_bf16(acc[row][j]);
            *(u16x8*)&W[(size_t)(o0 + row) * K_TOT + k0] = o8;
        }
    }
}

// raw barrier: memory clobbers pin LDS/VMEM ops; sched_barrier(0) (used at phase
// boxes below) pins the register-only MFMAs that "memory" cannot order (rule #18).
#define BARRIER() do { asm volatile("" ::: "memory"); \
                       __builtin_amdgcn_s_barrier(); \
                       asm volatile("" ::: "memory"); } while (0)
#define WAITL0()  asm volatile("s_waitcnt lgkmcnt(0)" ::: "memory")
#define SCHED0()  __builtin_amdgcn_sched_barrier(0)

// ---------------- C[m][n] = sum_k A[m][k]*B[n][k] + bias[n]  (bf16 K-major) ----------------
// 256x256 tile, BK=64, 8 waves (2Mx4N), 4 phases/K-tile (kk-split quadrants so ds_reads
// balance to {8,8,4,4} per phase), counted vmcnt(4) once per tile.
// LDS: 2 buf x {A,B} x 2 halves x [128 rows][64 cols] bf16 = 128 KB.
// Swizzle: row stride is 128 B (full bank wrap) -> store k-slot s of row r at slot s^(r&7).
// Staging pre-swizzles the GLOBAL source; LDS dst stays linear (global_load_lds constraint).
__global__ __launch_bounds__(512, 2) void gemm_bt_kernel(const unsigned short* __restrict__ A,
                                                         const unsigned short* __restrict__ B,
                                                         const float* __restrict__ bias,
                                                         float* __restrict__ C) {
    __shared__ unsigned short As[2][2][128 * BK];   // [buf][half][row*64+col] 64 KB
    __shared__ unsigned short Bs[2][2][128 * BK];   // 64 KB

    const int tid  = (int)threadIdx.x;
    const int wave = tid >> 6;        // 0..7
    const int lane = tid & 63;
    const int wm   = wave >> 2;       // 0..1 : A half / 128-row strip
    const int wn   = wave & 3;        // 0..3 : 64-col strip
    const int wbh  = wn >> 1;         // B half
    const int wbr  = (wn & 1) * 64;   // row base within B half

    // XCD-bijective swizzle: nwg=512, 8 XCDs, 64 contiguous tiles per XCD
    int lin = (int)(blockIdx.y * gridDim.x + blockIdx.x);
    lin = (lin & 7) * 64 + (lin >> 3);
    const int tile_n = (lin & 15) * BN;   // 16 N-tiles
    const int tile_m = (lin >> 4) * BM;   // 32 M-tiles

    // staging: instr covers rows i*64 + tid/8 of a half; lane's 16B chunk fetches
    // global k-group (tid&7) ^ (row&7)  (inverse swizzle applied at the source)
    const int srow  = tid >> 3;                         // 0..63
    const int sk    = ((tid & 7) ^ (srow & 7)) * 8;     // elem offset in 64-col group
    const int wbase = wave * 512;                       // wave-uniform LDS elem base

    // fragment-read constants (mfma_16x16x32: lane = quad*16+l16, A row=l16, k=quad*8)
    const int l16  = lane & 15;
    const int quad = lane >> 4;
    const int sw   = l16 & 7;
    const int slot0 = ((quad ^ sw) * 8);          // physical slot for k-slot quad   (kk=0)
    const int slot1 = (((4 + quad) ^ sw) * 8);    // physical slot for k-slot 4+quad (kk=1)

    const unsigned short* aBase = A + (size_t)(tile_m + srow) * K_TOT + sk;
    const unsigned short* bBase = B + (size_t)(tile_n + srow) * K_TOT + sk;

#define STAGE_A(d, h, t) do { \
    gload_lds16(aBase + (size_t)((h) * 128) * K_TOT + (size_t)(t) * BK, &As[d][h][wbase]); \
    gload_lds16(aBase + (size_t)((h) * 128 + 64) * K_TOT + (size_t)(t) * BK, &As[d][h][4096 + wbase]); \
  } while (0)
#define STAGE_B(d, h, t) do { \
    gload_lds16(bBase + (size_t)((h) * 128) * K_TOT + (size_t)(t) * BK, &Bs[d][h][wbase]); \
    gload_lds16(bBase + (size_t)((h) * 128 + 64) * K_TOT + (size_t)(t) * BK, &Bs[d][h][4096 + wbase]); \
  } while (0)

    f32x4 acc[8][4];
#pragma unroll
    for (int i = 0; i < 8; i++)
#pragma unroll
        for (int j = 0; j < 4; j++) { f32x4 z = {0.f, 0.f, 0.f, 0.f}; acc[i][j] = z; }

    // prologue: tile0 fully + A(1); vmcnt(4) leaves A(1)'s 4 loads in flight
    STAGE_A(0, 0, 0); STAGE_A(0, 1, 0);
    STAGE_B(0, 0, 0); STAGE_B(0, 1, 0);
    STAGE_A(1, 0, 1); STAGE_A(1, 1, 1);
    asm volatile("s_waitcnt vmcnt(4)" ::: "memory");
    BARRIER();

    for (int t = 0; t < NT; ++t) {
        const int cur = t & 1, nxt = cur ^ 1;
        const unsigned short* __restrict__ Ah = &As[cur][wm][l16 * BK];
        const unsigned short* __restrict__ Bh = &Bs[cur][wbh][(wbr + l16) * BK];

        bf16x8 bA[4], bB[4], aF[4];

        // ---- P1: stage B0(t+1); read bA (all ni, kk0) + af[0-3] kk0; MFMA acc[0-3][*] kk0 ----
        if (t + 1 < NT) STAGE_B(nxt, 0, t + 1);
#pragma unroll
        for (int ni = 0; ni < 4; ni++) bA[ni] = *(const bf16x8*)&Bh[(ni * 16) * BK + slot0];
#pragma unroll
        for (int mi = 0; mi < 4; mi++) aF[mi] = *(const bf16x8*)&Ah[(mi * 16) * BK + slot0];
        BARRIER();
        WAITL0();
        SCHED0();
        __builtin_amdgcn_s_setprio(1);
#pragma unroll
        for (int mi = 0; mi < 4; mi++)
#pragma unroll
            for (int ni = 0; ni < 4; ni++)
                acc[mi][ni] = __builtin_amdgcn_mfma_f32_16x16x32_bf16(aF[mi], bA[ni], acc[mi][ni], 0, 0, 0);
        __builtin_amdgcn_s_setprio(0);
        SCHED0();
        BARRIER();

        // ---- P2: stage B1(t+1); read bB (all ni, kk1) + af[0-3] kk1; MFMA acc[0-3][*] kk1 ----
        if (t + 1 < NT) STAGE_B(nxt, 1, t + 1);
#pragma unroll
        for (int ni = 0; ni < 4; ni++) bB[ni] = *(const bf16x8*)&Bh[(ni * 16) * BK + slot1];
#pragma unroll
        for (int mi = 0; mi < 4; mi++) aF[mi] = *(const bf16x8*)&Ah[(mi * 16) * BK + slot1];
        BARRIER();
        WAITL0();
        SCHED0();
        __builtin_amdgcn_s_setprio(1);
#pragma unroll
        for (int mi = 0; mi < 4; mi++)
#pragma unroll
            for (int ni = 0; ni < 4; ni++)
                acc[mi][ni] = __builtin_amdgcn_mfma_f32_16x16x32_bf16(aF[mi], bB[ni], acc[mi][ni], 0, 0, 0);
        __builtin_amdgcn_s_setprio(0);
        SCHED0();
        BARRIER();

        // ---- P3: read af[4-7] kk0; MFMA acc[4-7][*] kk0 (reuses bA) ----
#pragma unroll
        for (int mi = 0; mi < 4; mi++) aF[mi] = *(const bf16x8*)&Ah[((mi + 4) * 16) * BK + slot0];
        BARRIER();
        WAITL0();
        SCHED0();
        __builtin_amdgcn_s_setprio(1);
#pragma unroll
        for (int mi = 0; mi < 4; mi++)
#pragma unroll
            for (int ni = 0; ni < 4; ni++)
                acc[mi + 4][ni] = __builtin_amdgcn_mfma_f32_16x16x32_bf16(aF[mi], bA[ni], acc[mi + 4][ni], 0, 0, 0);
        __builtin_amdgcn_s_setprio(0);
        SCHED0();
        BARRIER();

        // ---- P4: read af[4-7] kk1; stage A(t+2) into buf[cur]; MFMA acc[4-7][*] kk1 (reuses bB);
        //      counted vmcnt ONCE per tile ----
#pragma unroll
        for (int mi = 0; mi < 4; mi++) aF[mi] = *(const bf16x8*)&Ah[((mi + 4) * 16) * BK + slot1];
        BARRIER();
        if (t + 2 < NT) { STAGE_A(cur, 0, t + 2); STAGE_A(cur, 1, t + 2); }
        WAITL0();
        SCHED0();
        __builtin_amdgcn_s_setprio(1);
#pragma unroll
        for (int mi = 0; mi < 4; mi++)
#pragma unroll
            for (int ni = 0; ni < 4; ni++)
                acc[mi + 4][ni] = __builtin_amdgcn_mfma_f32_16x16x32_bf16(aF[mi], bB[ni], acc[mi + 4][ni], 0, 0, 0);
        __builtin_amdgcn_s_setprio(0);
        SCHED0();
        if (t + 1 < NT) {
            if (t + 2 < NT) asm volatile("s_waitcnt vmcnt(4)" ::: "memory");  // A(t+1),B(t+1) landed; A(t+2) in flight
            else            asm volatile("s_waitcnt vmcnt(0)" ::: "memory");  // last-but-one tile: drain
        }
        BARRIER();
    }

    // epilogue: D row=(quad*4+r), col=l16 within each 16x16 tile
#pragma unroll
    for (int ni = 0; ni < 4; ni++) {
        const int col = tile_n + wn * 64 + ni * 16 + l16;
        const float bv = bias[col];
#pragma unroll
        for (int mi = 0; mi < 8; mi++) {
#pragma unroll
            for (int r = 0; r < 4; r++) {
                const int row = tile_m + wm * 128 + mi * 16 + quad * 4 + r;
                C[(size_t)row * N_TOT + col] = acc[mi][ni][r] + bv;
            }
        }
    }
#undef STAGE_A
#undef STAGE_B
}

extern "C" void kernel_launch(void* const* d_in, const int* in_sizes, int n_in,
                              void* d_out, int out_size, void* d_ws, size_t ws_size,
                              hipStream_t stream) {
    const float* x      = (const float*)d_in[0];
    const int*   q      = (const int*)d_in[1];
    const float* scales = (const float*)d_in[2];
    const float* up     = (const float*)d_in[3];
    const float* down   = (const float*)d_in[4];
    const float* bias   = (const float*)d_in[5];
    float* out = (float*)d_out;

    unsigned short* xb = (unsigned short*)d_ws;                 // 8192*4096 bf16 = 64 MB
    unsigned short* wb = xb + (size_t)M_TOT * K_TOT;            // 4096*4096 bf16 = 32 MB

    const int n8 = M_TOT * K_TOT / 8;
    convert_x_kernel<<<n8 / 256, 256, 0, stream>>>(x, xb, n8);
    build_w_kernel<<<N_TOT / 4, 256, 0, stream>>>(q, scales, up, down, wb);
    gemm_bt_kernel<<<dim3(N_TOT / BN, M_TOT / BM), 512, 0, stream>>>(xb, wb, bias, out);
}

// Round 4
// 542.431 us; speedup vs baseline: 1.1326x; 1.1024x over previous
//
#include <hip/hip_runtime.h>
#include <cstdint>
#include <cstddef>

#define M_TOT 8192
#define N_TOT 4096
#define K_TOT 4096
#define RANK  16

// ---- 256x256 8-phase GEMM geometry ----
#define BM 256
#define BN 256
#define BK 64
#define NT (K_TOT / BK)   // 64 K-tiles

typedef float f32x4 __attribute__((ext_vector_type(4)));
typedef __bf16 bf16x8 __attribute__((ext_vector_type(8)));
typedef unsigned short u16x8 __attribute__((ext_vector_type(8)));

__device__ __forceinline__ unsigned short f32_to_bf16(float f) {
    union { float f; uint32_t u; } v; v.f = f;
    uint32_t r = v.u + (0x7fffu + ((v.u >> 16) & 1u));
    return (unsigned short)(r >> 16);
}

// width-16 async global->LDS. dst is wave-uniform base; HW writes lane i at base + i*16B.
__device__ __forceinline__ void gload_lds16(const void* g, void* l) {
    __builtin_amdgcn_global_load_lds(
        (const __attribute__((address_space(1))) void*)g,
        (__attribute__((address_space(3))) void*)l,
        16, 0, 0);
}

// LDS byte address (as(3) pointers are the raw LDS byte offset)
__device__ __forceinline__ unsigned lds_addr(const void* p) {
    return (unsigned)(uintptr_t)(const __attribute__((address_space(3))) void*)p;
}

// Inline-asm ds_read_b128: OPAQUE to the compiler's alias analysis, so
// SIInsertWaitcnts cannot tie it to outstanding global_load_lds (LDS-DMA) ops
// and will NOT insert implicit vmcnt drains before it (the R0-R3 serializer).
// Rule #18: consumers must be fenced by explicit lgkmcnt(0) + sched_barrier(0).
__device__ __forceinline__ bf16x8 dsr(unsigned addr) {
    bf16x8 r;
    asm volatile("ds_read_b128 %0, %1" : "=v"(r) : "v"(addr));
    return r;
}

// ---------------- x fp32 -> bf16, 8 elems/thread, 16B stores ----------------
__global__ __launch_bounds__(256) void convert_x_kernel(const float* __restrict__ x,
                                                        unsigned short* __restrict__ xb,
                                                        int n8) {
    int i = blockIdx.x * 256 + threadIdx.x;
    if (i >= n8) return;
    float4 a = ((const float4*)x)[2 * (size_t)i];
    float4 b = ((const float4*)x)[2 * (size_t)i + 1];
    u16x8 o;
    o[0] = f32_to_bf16(a.x); o[1] = f32_to_bf16(a.y);
    o[2] = f32_to_bf16(a.z); o[3] = f32_to_bf16(a.w);
    o[4] = f32_to_bf16(b.x); o[5] = f32_to_bf16(b.y);
    o[6] = f32_to_bf16(b.z); o[7] = f32_to_bf16(b.w);
    *(u16x8*)&xb[(size_t)i * 8] = o;
}

// ---- W = dequant(q,scales) + up@down, bf16 [OUT][IN]. 4 rows/block. ----
__global__ __launch_bounds__(256) void build_w_kernel(const int* __restrict__ q,
                                                      const float* __restrict__ scales,
                                                      const float* __restrict__ up,
                                                      const float* __restrict__ down,
                                                      unsigned short* __restrict__ W) {
    const int o0 = blockIdx.x * 4;
    const int t = threadIdx.x;
    __shared__ float u[4][RANK];
    if (t < 64) u[t >> 4][t & 15] = up[(o0 + (t >> 4)) * RANK + (t & 15)];
    __syncthreads();

#pragma unroll
    for (int cc = 0; cc < 2; cc++) {
        const int c = t + 256 * cc;        // 8-elem chunk index, 0..511
        const int k0 = c * 8;
        float acc[4][8];
#pragma unroll
        for (int row = 0; row < 4; row++) {
            const int o = o0 + row;
            int4 qa = *(const int4*)&q[(size_t)o * K_TOT + k0];
            int4 qb = *(const int4*)&q[(size_t)o * K_TOT + k0 + 4];
            const float s = scales[o * (K_TOT / 32) + (k0 >> 5)];
            acc[row][0] = (float)(qa.x - 128) * s;
            acc[row][1] = (float)(qa.y - 128) * s;
            acc[row][2] = (float)(qa.z - 128) * s;
            acc[row][3] = (float)(qa.w - 128) * s;
            acc[row][4] = (float)(qb.x - 128) * s;
            acc[row][5] = (float)(qb.y - 128) * s;
            acc[row][6] = (float)(qb.z - 128) * s;
            acc[row][7] = (float)(qb.w - 128) * s;
        }
#pragma unroll
        for (int r = 0; r < RANK; r++) {
            float4 da = *(const float4*)&down[r * K_TOT + k0];
            float4 db = *(const float4*)&down[r * K_TOT + k0 + 4];
#pragma unroll
            for (int row = 0; row < 4; row++) {
                const float ur = u[row][r];
                acc[row][0] += ur * da.x; acc[row][1] += ur * da.y;
                acc[row][2] += ur * da.z; acc[row][3] += ur * da.w;
                acc[row][4] += ur * db.x; acc[row][5] += ur * db.y;
                acc[row][6] += ur * db.z; acc[row][7] += ur * db.w;
            }
        }
#pragma unroll
        for (int row = 0; row < 4; row++) {
            u16x8 o8;
#pragma unroll
            for (int j = 0; j < 8; j++) o8[j] = f32_to_bf16(acc[row][j]);
            *(u16x8*)&W[(size_t)(o0 + row) * K_TOT + k0] = o8;
        }
    }
}

// raw barrier (no vmcnt drain); memory clobbers pin LDS-DMA/VMEM issue order.
#define BARRIER() do { asm volatile("" ::: "memory"); \
                       __builtin_amdgcn_s_barrier(); \
                       asm volatile("" ::: "memory"); } while (0)
#define WAITL0()  asm volatile("s_waitcnt lgkmcnt(0)" ::: "memory")
#define VMCNT0()  asm volatile("s_waitcnt vmcnt(0)" ::: "memory")
#define SCHED0()  __builtin_amdgcn_sched_barrier(0)

// ---------------- C[m][n] = sum_k A[m][k]*B[n][k] + bias[n]  (bf16 K-major) ----------------
// 256x256 tile, BK=64, 8 waves (2Mx4N), 4 phases/K-tile; per phase:
//   {asm ds_reads; stage half-tile(s) of t+1; barrier; lgkmcnt(0); sched0; MFMA x16; sched0; barrier}
// All of tile t+1 staged during t's P1-P3 (into buf[nxt], never read this tile); ONE
// vmcnt(0) at tile end — issue-to-wait distance >= ~1300 cyc so the drain is ~free.
// LDS: 2 buf x {A,B} x 2 halves x [128 rows][64 cols] bf16 = 128 KB.
// Swizzle: store 16B k-slot s of row r at slot s^(r&7); staging pre-swizzles the GLOBAL
// source (global_load_lds dst must stay linear); reads apply the same XOR.
__global__ __launch_bounds__(512, 2) void gemm_bt_kernel(const unsigned short* __restrict__ A,
                                                         const unsigned short* __restrict__ B,
                                                         const float* __restrict__ bias,
                                                         float* __restrict__ C) {
    __shared__ unsigned short As[2][2][128 * BK];   // [buf][half][row*64+col] 64 KB
    __shared__ unsigned short Bs[2][2][128 * BK];   // 64 KB

    const int tid  = (int)threadIdx.x;
    const int wave = tid >> 6;        // 0..7
    const int lane = tid & 63;
    const int wm   = wave >> 2;       // 0..1 : A half / 128-row strip
    const int wn   = wave & 3;        // 0..3 : 64-col strip
    const int wbh  = wn >> 1;         // B half
    const int wbr  = (wn & 1) * 64;   // row base within B half

    // XCD-bijective swizzle: nwg=512, 8 XCDs, 64 contiguous tiles per XCD
    int lin = (int)(blockIdx.y * gridDim.x + blockIdx.x);
    lin = (lin & 7) * 64 + (lin >> 3);
    const int tile_n = (lin & 15) * BN;   // 16 N-tiles
    const int tile_m = (lin >> 4) * BM;   // 32 M-tiles

    // staging: instr covers rows i*64 + tid/8 of a half; lane's 16B chunk fetches
    // global k-group (tid&7) ^ (row&7)  (inverse swizzle applied at the source)
    const int srow  = tid >> 3;                         // 0..63
    const int sk    = ((tid & 7) ^ (srow & 7)) * 8;     // elem offset in 64-col group
    const int wbase = wave * 512;                       // wave-uniform LDS elem base

    // fragment-read constants (mfma_16x16x32: lane = quad*16+l16, A row=l16, k=quad*8)
    const int l16  = lane & 15;
    const int quad = lane >> 4;
    const int sw   = l16 & 7;
    const int slot0 = ((quad ^ sw) * 8);          // physical slot for k-slot quad   (kk=0)
    const int slot1 = (((4 + quad) ^ sw) * 8);    // physical slot for k-slot 4+quad (kk=1)

    const unsigned short* aBase = A + (size_t)(tile_m + srow) * K_TOT + sk;
    const unsigned short* bBase = B + (size_t)(tile_n + srow) * K_TOT + sk;

#define STAGE_A(d, h, t) do { \
    gload_lds16(aBase + (size_t)((h) * 128) * K_TOT + (size_t)(t) * BK, &As[d][h][wbase]); \
    gload_lds16(aBase + (size_t)((h) * 128 + 64) * K_TOT + (size_t)(t) * BK, &As[d][h][4096 + wbase]); \
  } while (0)
#define STAGE_B(d, h, t) do { \
    gload_lds16(bBase + (size_t)((h) * 128) * K_TOT + (size_t)(t) * BK, &Bs[d][h][wbase]); \
    gload_lds16(bBase + (size_t)((h) * 128 + 64) * K_TOT + (size_t)(t) * BK, &Bs[d][h][4096 + wbase]); \
  } while (0)

    f32x4 acc[8][4];
#pragma unroll
    for (int i = 0; i < 8; i++)
#pragma unroll
        for (int j = 0; j < 4; j++) { f32x4 z = {0.f, 0.f, 0.f, 0.f}; acc[i][j] = z; }

    // prologue: stage tile 0 fully; long-distance drain pattern starts at t=0
    STAGE_A(0, 0, 0); STAGE_A(0, 1, 0);
    STAGE_B(0, 0, 0); STAGE_B(0, 1, 0);
    VMCNT0();
    BARRIER();

    for (int t = 0; t < NT; ++t) {
        const int cur = t & 1, nxt = cur ^ 1;

        // per-tile LDS byte bases (swizzled slot folded in; row offsets added per read)
        const unsigned AhB = lds_addr(&As[cur][wm][l16 * BK]);
        const unsigned BhB = lds_addr(&Bs[cur][wbh][(wbr + l16) * BK]);
        const unsigned a0 = AhB + slot0 * 2, a1 = AhB + slot1 * 2;
        const unsigned b0 = BhB + slot0 * 2, b1 = BhB + slot1 * 2;

        bf16x8 bA[4], bB[4], aK[4];

        // ---- P1: reads (bA = B kk0, aK = A[0-3] kk0); stage B0(t+1); MFMA acc[0-3][*] kk0 ----
#pragma unroll
        for (int ni = 0; ni < 4; ni++) bA[ni] = dsr(b0 + ni * 2048);
#pragma unroll
        for (int mi = 0; mi < 4; mi++) aK[mi] = dsr(a0 + mi * 2048);
        if (t + 1 < NT) STAGE_B(nxt, 0, t + 1);
        BARRIER();
        WAITL0();
        SCHED0();
        __builtin_amdgcn_s_setprio(1);
#pragma unroll
        for (int mi = 0; mi < 4; mi++)
#pragma unroll
            for (int ni = 0; ni < 4; ni++)
                acc[mi][ni] = __builtin_amdgcn_mfma_f32_16x16x32_bf16(aK[mi], bA[ni], acc[mi][ni], 0, 0, 0);
        __builtin_amdgcn_s_setprio(0);
        SCHED0();
        BARRIER();

        // ---- P2: reads (bB = B kk1, aK = A[0-3] kk1); stage B1(t+1); MFMA acc[0-3][*] kk1 ----
#pragma unroll
        for (int ni = 0; ni < 4; ni++) bB[ni] = dsr(b1 + ni * 2048);
#pragma unroll
        for (int mi = 0; mi < 4; mi++) aK[mi] = dsr(a1 + mi * 2048);
        if (t + 1 < NT) STAGE_B(nxt, 1, t + 1);
        BARRIER();
        WAITL0();
        SCHED0();
        __builtin_amdgcn_s_setprio(1);
#pragma unroll
        for (int mi = 0; mi < 4; mi++)
#pragma unroll
            for (int ni = 0; ni < 4; ni++)
                acc[mi][ni] = __builtin_amdgcn_mfma_f32_16x16x32_bf16(aK[mi], bB[ni], acc[mi][ni], 0, 0, 0);
        __builtin_amdgcn_s_setprio(0);
        SCHED0();
        BARRIER();

        // ---- P3: reads (aK = A[4-7] kk0); stage A0+A1(t+1); MFMA acc[4-7][*] kk0 (reuses bA) ----
#pragma unroll
        for (int mi = 0; mi < 4; mi++) aK[mi] = dsr(a0 + 8192 + mi * 2048);
        if (t + 1 < NT) { STAGE_A(nxt, 0, t + 1); STAGE_A(nxt, 1, t + 1); }
        BARRIER();
        WAITL0();
        SCHED0();
        __builtin_amdgcn_s_setprio(1);
#pragma unroll
        for (int mi = 0; mi < 4; mi++)
#pragma unroll
            for (int ni = 0; ni < 4; ni++)
                acc[mi + 4][ni] = __builtin_amdgcn_mfma_f32_16x16x32_bf16(aK[mi], bA[ni], acc[mi + 4][ni], 0, 0, 0);
        __builtin_amdgcn_s_setprio(0);
        SCHED0();
        BARRIER();

        // ---- P4: reads (aK = A[4-7] kk1); MFMA acc[4-7][*] kk1 (reuses bB); tile-end drain ----
#pragma unroll
        for (int mi = 0; mi < 4; mi++) aK[mi] = dsr(a1 + 8192 + mi * 2048);
        BARRIER();
        WAITL0();
        SCHED0();
        __builtin_amdgcn_s_setprio(1);
#pragma unroll
        for (int mi = 0; mi < 4; mi++)
#pragma unroll
            for (int ni = 0; ni < 4; ni++)
                acc[mi + 4][ni] = __builtin_amdgcn_mfma_f32_16x16x32_bf16(aK[mi], bB[ni], acc[mi + 4][ni], 0, 0, 0);
        __builtin_amdgcn_s_setprio(0);
        SCHED0();
        VMCNT0();       // t+1's 8 loads issued >= 1-3 phases ago: drain is ~free, and
        BARRIER();      // barrier makes their LDS writes visible before t+1's reads
    }

    // epilogue: D row=(quad*4+r), col=l16 within each 16x16 tile
#pragma unroll
    for (int ni = 0; ni < 4; ni++) {
        const int col = tile_n + wn * 64 + ni * 16 + l16;
        const float bv = bias[col];
#pragma unroll
        for (int mi = 0; mi < 8; mi++) {
#pragma unroll
            for (int r = 0; r < 4; r++) {
                const int row = tile_m + wm * 128 + mi * 16 + quad * 4 + r;
                C[(size_t)row * N_TOT + col] = acc[mi][ni][r] + bv;
            }
        }
    }
#undef STAGE_A
#undef STAGE_B
}

extern "C" void kernel_launch(void* const* d_in, const int* in_sizes, int n_in,
                              void* d_out, int out_size, void* d_ws, size_t ws_size,
                              hipStream_t stream) {
    const float* x      = (const float*)d_in[0];
    const int*   q      = (const int*)d_in[1];
    const float* scales = (const float*)d_in[2];
    const float* up     = (const float*)d_in[3];
    const float* down   = (const float*)d_in[4];
    const float* bias   = (const float*)d_in[5];
    float* out = (float*)d_out;

    unsigned short* xb = (unsigned short*)d_ws;                 // 8192*4096 bf16 = 64 MB
    unsigned short* wb = xb + (size_t)M_TOT * K_TOT;            // 4096*4096 bf16 = 32 MB

    const int n8 = M_TOT * K_TOT / 8;
    convert_x_kernel<<<n8 / 256, 256, 0, stream>>>(x, xb, n8);
    build_w_kernel<<<N_TOT / 4, 256, 0, stream>>>(q, scales, up, down, wb);
    gemm_bt_kernel<<<dim3(N_TOT / BN, M_TOT / BM), 512, 0, stream>>>(xb, wb, bias, out);
}

// Round 5
// 527.639 us; speedup vs baseline: 1.1643x; 1.0280x over previous
//
#include <hip/hip_runtime.h>
#include <cstdint>
#include <cstddef>

#define M_TOT 8192
#define N_TOT 4096
#define K_TOT 4096
#define RANK  16

// ---- 256x256 GEMM geometry, 1-barrier-per-tile counted-lgkm schedule ----
#define BM 256
#define BN 256
#define BK 64
#define NT (K_TOT / BK)   // 64 K-tiles

typedef float f32x4 __attribute__((ext_vector_type(4)));
typedef __bf16 bf16x8 __attribute__((ext_vector_type(8)));
typedef unsigned short u16x8 __attribute__((ext_vector_type(8)));

__device__ __forceinline__ unsigned short f32_to_bf16(float f) {
    union { float f; uint32_t u; } v; v.f = f;
    uint32_t r = v.u + (0x7fffu + ((v.u >> 16) & 1u));
    return (unsigned short)(r >> 16);
}

// width-16 async global->LDS. dst is wave-uniform base; HW writes lane i at base + i*16B.
__device__ __forceinline__ void gload_lds16(const void* g, void* l) {
    __builtin_amdgcn_global_load_lds(
        (const __attribute__((address_space(1))) void*)g,
        (__attribute__((address_space(3))) void*)l,
        16, 0, 0);
}

// LDS byte address (as(3) pointers are the raw LDS byte offset)
__device__ __forceinline__ unsigned lds_addr(const void* p) {
    return (unsigned)(uintptr_t)(const __attribute__((address_space(3))) void*)p;
}

// Inline-asm ds_read_b128: opaque to alias analysis -> no implicit vmcnt drains
// (the R0-R3 serializer). Volatile asm preserves mutual order, so issue order ==
// lgkmcnt retire order. Consumers fenced by counted lgkmcnt + sched_barrier(0).
__device__ __forceinline__ bf16x8 dsr(unsigned addr) {
    bf16x8 r;
    asm volatile("ds_read_b128 %0, %1" : "=v"(r) : "v"(addr));
    return r;
}

// ---------------- x fp32 -> bf16, 8 elems/thread, 16B stores ----------------
__global__ __launch_bounds__(256) void convert_x_kernel(const float* __restrict__ x,
                                                        unsigned short* __restrict__ xb,
                                                        int n8) {
    int i = blockIdx.x * 256 + threadIdx.x;
    if (i >= n8) return;
    float4 a = ((const float4*)x)[2 * (size_t)i];
    float4 b = ((const float4*)x)[2 * (size_t)i + 1];
    u16x8 o;
    o[0] = f32_to_bf16(a.x); o[1] = f32_to_bf16(a.y);
    o[2] = f32_to_bf16(a.z); o[3] = f32_to_bf16(a.w);
    o[4] = f32_to_bf16(b.x); o[5] = f32_to_bf16(b.y);
    o[6] = f32_to_bf16(b.z); o[7] = f32_to_bf16(b.w);
    *(u16x8*)&xb[(size_t)i * 8] = o;
}

// ---- W = dequant(q,scales) + up@down, bf16 [OUT][IN]. 4 rows/block. ----
__global__ __launch_bounds__(256) void build_w_kernel(const int* __restrict__ q,
                                                      const float* __restrict__ scales,
                                                      const float* __restrict__ up,
                                                      const float* __restrict__ down,
                                                      unsigned short* __restrict__ W) {
    const int o0 = blockIdx.x * 4;
    const int t = threadIdx.x;
    __shared__ float u[4][RANK];
    if (t < 64) u[t >> 4][t & 15] = up[(o0 + (t >> 4)) * RANK + (t & 15)];
    __syncthreads();

#pragma unroll
    for (int cc = 0; cc < 2; cc++) {
        const int c = t + 256 * cc;        // 8-elem chunk index, 0..511
        const int k0 = c * 8;
        float acc[4][8];
#pragma unroll
        for (int row = 0; row < 4; row++) {
            const int o = o0 + row;
            int4 qa = *(const int4*)&q[(size_t)o * K_TOT + k0];
            int4 qb = *(const int4*)&q[(size_t)o * K_TOT + k0 + 4];
            const float s = scales[o * (K_TOT / 32) + (k0 >> 5)];
            acc[row][0] = (float)(qa.x - 128) * s;
            acc[row][1] = (float)(qa.y - 128) * s;
            acc[row][2] = (float)(qa.z - 128) * s;
            acc[row][3] = (float)(qa.w - 128) * s;
            acc[row][4] = (float)(qb.x - 128) * s;
            acc[row][5] = (float)(qb.y - 128) * s;
            acc[row][6] = (float)(qb.z - 128) * s;
            acc[row][7] = (float)(qb.w - 128) * s;
        }
#pragma unroll
        for (int r = 0; r < RANK; r++) {
            float4 da = *(const float4*)&down[r * K_TOT + k0];
            float4 db = *(const float4*)&down[r * K_TOT + k0 + 4];
#pragma unroll
            for (int row = 0; row < 4; row++) {
                const float ur = u[row][r];
                acc[row][0] += ur * da.x; acc[row][1] += ur * da.y;
                acc[row][2] += ur * da.z; acc[row][3] += ur * da.w;
                acc[row][4] += ur * db.x; acc[row][5] += ur * db.y;
                acc[row][6] += ur * db.z; acc[row][7] += ur * db.w;
            }
        }
#pragma unroll
        for (int row = 0; row < 4; row++) {
            u16x8 o8;
#pragma unroll
            for (int j = 0; j < 8; j++) o8[j] = f32_to_bf16(acc[row][j]);
            *(u16x8*)&W[(size_t)(o0 + row) * K_TOT + k0] = o8;
        }
    }
}

// raw barrier (no vmcnt drain); memory clobbers pin LDS-DMA/VMEM issue order.
#define BARRIER() do { asm volatile("" ::: "memory"); \
                       __builtin_amdgcn_s_barrier(); \
                       asm volatile("" ::: "memory"); } while (0)
#define WAITLG8() asm volatile("s_waitcnt lgkmcnt(8)" ::: "memory")
#define WAITLG4() asm volatile("s_waitcnt lgkmcnt(4)" ::: "memory")
#define WAITLG0() asm volatile("s_waitcnt lgkmcnt(0)" ::: "memory")
#define VMCNT0()  asm volatile("s_waitcnt vmcnt(0)" ::: "memory")
#define SCHED0()  __builtin_amdgcn_sched_barrier(0)

// ---------------- C[m][n] = sum_k A[m][k]*B[n][k] + bias[n]  (bf16 K-major) ----------------
// 256x256 tile, BK=64, 8 waves (2Mx4N). ONE barrier per K-tile. Per tile, per wave:
//   stage all 8 gloads of t+1 -> issue R1(8)+R2(8) ds_reads -> lgkm(8) Q1 MFMA ->
//   issue R3(8) -> lgkm(8) Q2 -> lgkm(4) Q3 -> lgkm(0) Q4 -> vmcnt(0) -> barrier.
// Counted lgkm lets later reads drain DURING earlier MFMA clusters (LDS pipe ~2300cyc
// hides under MFMA pipe ~2480cyc). Intra-tile barriers removed: reads hit buf[cur]
// (drained at last boundary), stage-writes hit buf[nxt] (read next tile) -> no
// intra-tile cross-wave hazard. Per-wave lgkm(0) before Q4 + boundary barrier
// guarantees block-wide reads done before next tile's stage-writes (WAR).
// LDS: 2 buf x {A,B} x 2 halves x [128 rows][64 cols] bf16 = 128 KB.
// Swizzle: store 16B k-slot s of row r at slot s^(r&7); staging pre-swizzles the GLOBAL
// source (global_load_lds dst must stay linear); reads apply the same XOR.
__global__ __launch_bounds__(512, 2) void gemm_bt_kernel(const unsigned short* __restrict__ A,
                                                         const unsigned short* __restrict__ B,
                                                         const float* __restrict__ bias,
                                                         float* __restrict__ C) {
    __shared__ unsigned short As[2][2][128 * BK];   // [buf][half][row*64+col] 64 KB
    __shared__ unsigned short Bs[2][2][128 * BK];   // 64 KB

    const int tid  = (int)threadIdx.x;
    const int wave = tid >> 6;        // 0..7
    const int lane = tid & 63;
    const int wm   = wave >> 2;       // 0..1 : A half / 128-row strip
    const int wn   = wave & 3;        // 0..3 : 64-col strip
    const int wbh  = wn >> 1;         // B half
    const int wbr  = (wn & 1) * 64;   // row base within B half

    // XCD-bijective swizzle: nwg=512, 8 XCDs, 64 contiguous tiles per XCD
    int lin = (int)(blockIdx.y * gridDim.x + blockIdx.x);
    lin = (lin & 7) * 64 + (lin >> 3);
    const int tile_n = (lin & 15) * BN;   // 16 N-tiles
    const int tile_m = (lin >> 4) * BM;   // 32 M-tiles

    // staging: instr covers rows i*64 + tid/8 of a half; lane's 16B chunk fetches
    // global k-group (tid&7) ^ (row&7)  (inverse swizzle applied at the source)
    const int srow  = tid >> 3;                         // 0..63
    const int sk    = ((tid & 7) ^ (srow & 7)) * 8;     // elem offset in 64-col group
    const int wbase = wave * 512;                       // wave-uniform LDS elem base

    // fragment-read constants (mfma_16x16x32: lane = quad*16+l16, A row=l16, k=quad*8)
    const int l16  = lane & 15;
    const int quad = lane >> 4;
    const int sw   = l16 & 7;
    const int slot0 = ((quad ^ sw) * 8);          // physical slot for k-slot quad   (kk=0)
    const int slot1 = (((4 + quad) ^ sw) * 8);    // physical slot for k-slot 4+quad (kk=1)

    const unsigned short* aBase = A + (size_t)(tile_m + srow) * K_TOT + sk;
    const unsigned short* bBase = B + (size_t)(tile_n + srow) * K_TOT + sk;

#define STAGE_A(d, h, t) do { \
    gload_lds16(aBase + (size_t)((h) * 128) * K_TOT + (size_t)(t) * BK, &As[d][h][wbase]); \
    gload_lds16(aBase + (size_t)((h) * 128 + 64) * K_TOT + (size_t)(t) * BK, &As[d][h][4096 + wbase]); \
  } while (0)
#define STAGE_B(d, h, t) do { \
    gload_lds16(bBase + (size_t)((h) * 128) * K_TOT + (size_t)(t) * BK, &Bs[d][h][wbase]); \
    gload_lds16(bBase + (size_t)((h) * 128 + 64) * K_TOT + (size_t)(t) * BK, &Bs[d][h][4096 + wbase]); \
  } while (0)

    f32x4 acc[8][4];
#pragma unroll
    for (int i = 0; i < 8; i++)
#pragma unroll
        for (int j = 0; j < 4; j++) { f32x4 z = {0.f, 0.f, 0.f, 0.f}; acc[i][j] = z; }

    // prologue: stage tile 0 fully, drain, barrier
    STAGE_A(0, 0, 0); STAGE_A(0, 1, 0);
    STAGE_B(0, 0, 0); STAGE_B(0, 1, 0);
    VMCNT0();
    BARRIER();

    for (int t = 0; t < NT; ++t) {
        const int cur = t & 1, nxt = cur ^ 1;

        // stage ALL of tile t+1 up front: max vmcnt issue-to-drain distance (~full tile)
        if (t + 1 < NT) {
            STAGE_B(nxt, 0, t + 1); STAGE_B(nxt, 1, t + 1);
            STAGE_A(nxt, 0, t + 1); STAGE_A(nxt, 1, t + 1);
        }

        // per-tile LDS byte bases (swizzled slot folded in; row offsets added per read)
        const unsigned AhB = lds_addr(&As[cur][wm][l16 * BK]);
        const unsigned BhB = lds_addr(&Bs[cur][wbh][(wbr + l16) * BK]);
        const unsigned a0 = AhB + slot0 * 2, a1 = AhB + slot1 * 2;
        const unsigned b0 = BhB + slot0 * 2, b1 = BhB + slot1 * 2;

        bf16x8 bA[4], bB[4], aK0[4], aK1[4], aH0[4], aH1[4];

        // R1 (8 reads): bA = B kk0, aK0 = A[0-3] kk0   -> feeds Q1
#pragma unroll
        for (int ni = 0; ni < 4; ni++) bA[ni]  = dsr(b0 + ni * 2048);
#pragma unroll
        for (int mi = 0; mi < 4; mi++) aK0[mi] = dsr(a0 + mi * 2048);
        // R2 (8 reads): bB = B kk1, aK1 = A[0-3] kk1   -> feeds Q2
#pragma unroll
        for (int ni = 0; ni < 4; ni++) bB[ni]  = dsr(b1 + ni * 2048);
#pragma unroll
        for (int mi = 0; mi < 4; mi++) aK1[mi] = dsr(a1 + mi * 2048);

        // Q1: wait R1 only (R2 still draining during MFMAs)
        WAITLG8();
        SCHED0();
        __builtin_amdgcn_s_setprio(1);
#pragma unroll
        for (int mi = 0; mi < 4; mi++)
#pragma unroll
            for (int ni = 0; ni < 4; ni++)
                acc[mi][ni] = __builtin_amdgcn_mfma_f32_16x16x32_bf16(aK0[mi], bA[ni], acc[mi][ni], 0, 0, 0);
        __builtin_amdgcn_s_setprio(0);
        SCHED0();

        // R3 (8 reads): aH0 = A[4-7] kk0, aH1 = A[4-7] kk1   -> feeds Q3/Q4
#pragma unroll
        for (int mi = 0; mi < 4; mi++) aH0[mi] = dsr(a0 + 8192 + mi * 2048);
#pragma unroll
        for (int mi = 0; mi < 4; mi++) aH1[mi] = dsr(a1 + 8192 + mi * 2048);

        // Q2: wait R2 (outstanding <= R3's 8); R3 drains during MFMAs
        WAITLG8();
        SCHED0();
        __builtin_amdgcn_s_setprio(1);
#pragma unroll
        for (int mi = 0; mi < 4; mi++)
#pragma unroll
            for (int ni = 0; ni < 4; ni++)
                acc[mi][ni] = __builtin_amdgcn_mfma_f32_16x16x32_bf16(aK1[mi], bB[ni], acc[mi][ni], 0, 0, 0);
        __builtin_amdgcn_s_setprio(0);
        SCHED0();

        // Q3: wait first half of R3 (aH0); reuses bA
        WAITLG4();
        SCHED0();
        __builtin_amdgcn_s_setprio(1);
#pragma unroll
        for (int mi = 0; mi < 4; mi++)
#pragma unroll
            for (int ni = 0; ni < 4; ni++)
                acc[mi + 4][ni] = __builtin_amdgcn_mfma_f32_16x16x32_bf16(aH0[mi], bA[ni], acc[mi + 4][ni], 0, 0, 0);
        __builtin_amdgcn_s_setprio(0);
        SCHED0();

        // Q4: all reads done; reuses bB. lgkm(0) here also guarantees block-wide
        // read-completion before the boundary barrier (WAR vs next tile's stages).
        WAITLG0();
        SCHED0();
        __builtin_amdgcn_s_setprio(1);
#pragma unroll
        for (int mi = 0; mi < 4; mi++)
#pragma unroll
            for (int ni = 0; ni < 4; ni++)
                acc[mi + 4][ni] = __builtin_amdgcn_mfma_f32_16x16x32_bf16(aH1[mi], bB[ni], acc[mi + 4][ni], 0, 0, 0);
        __builtin_amdgcn_s_setprio(0);
        SCHED0();

        VMCNT0();       // t+1's 8 stage loads issued a full tile ago: ~free drain;
        BARRIER();      // boundary makes their LDS writes visible for t+1's reads
    }

    // epilogue: D row=(quad*4+r), col=l16 within each 16x16 tile
#pragma unroll
    for (int ni = 0; ni < 4; ni++) {
        const int col = tile_n + wn * 64 + ni * 16 + l16;
        const float bv = bias[col];
#pragma unroll
        for (int mi = 0; mi < 8; mi++) {
#pragma unroll
            for (int r = 0; r < 4; r++) {
                const int row = tile_m + wm * 128 + mi * 16 + quad * 4 + r;
                C[(size_t)row * N_TOT + col] = acc[mi][ni][r] + bv;
            }
        }
    }
#undef STAGE_A
#undef STAGE_B
}

extern "C" void kernel_launch(void* const* d_in, const int* in_sizes, int n_in,
                              void* d_out, int out_size, void* d_ws, size_t ws_size,
                              hipStream_t stream) {
    const float* x      = (const float*)d_in[0];
    const int*   q      = (const int*)d_in[1];
    const float* scales = (const float*)d_in[2];
    const float* up     = (const float*)d_in[3];
    const float* down   = (const float*)d_in[4];
    const float* bias   = (const float*)d_in[5];
    float* out = (float*)d_out;

    unsigned short* xb = (unsigned short*)d_ws;                 // 8192*4096 bf16 = 64 MB
    unsigned short* wb = xb + (size_t)M_TOT * K_TOT;            // 4096*4096 bf16 = 32 MB

    const int n8 = M_TOT * K_TOT / 8;
    convert_x_kernel<<<n8 / 256, 256, 0, stream>>>(x, xb, n8);
    build_w_kernel<<<N_TOT / 4, 256, 0, stream>>>(q, scales, up, down, wb);
    gemm_bt_kernel<<<dim3(N_TOT / BN, M_TOT / BM), 512, 0, stream>>>(xb, wb, bias, out);
}